// Round 6
// baseline (17180.026 us; speedup 1.0000x reference)
//
#include <hip/hip_runtime.h>
#include <math.h>

#define B_  32
#define T_  512
#define I_  128
#define H_  512
#define G4_ 2048   // 4*H
#define GB_ 64     // blocks per sync group (dependency-closed)

// ---------------------------------------------------------------------------
// Tiled fp32 GEMM: C[m][n] = sum_k A[m][k] * Bm[n][k]  (+ bias[n] if bias)
// ---------------------------------------------------------------------------
__global__ __launch_bounds__(256) void gemm_abt(
    const float* __restrict__ A, const float* __restrict__ Bm, float* __restrict__ C,
    const float* __restrict__ bias, long sA, long sB, long sC, int ldc)
{
  __shared__ float Al[64][65];
  __shared__ float Bl[64][65];
  const long z = blockIdx.z;
  A += z * sA; Bm += z * sB; C += z * sC;
  const int m0 = blockIdx.x * 64, n0 = blockIdx.y * 64;
  const int tid = threadIdx.x;
  const int tx = tid & 15, ty = tid >> 4;
  float acc[4][4] = {};

  for (int h = 0; h < 2; ++h) {
    const int k0 = h * 64;
    __syncthreads();
    #pragma unroll
    for (int s = 0; s < 4; ++s) {
      int idx = tid + s * 256;
      int m  = idx >> 4;
      int k4 = (idx & 15) << 2;
      float4 a4 = *(const float4*)&A[(long)(m0 + m) * 128 + k0 + k4];
      Al[k4 + 0][m] = a4.x; Al[k4 + 1][m] = a4.y; Al[k4 + 2][m] = a4.z; Al[k4 + 3][m] = a4.w;
      float4 b4 = *(const float4*)&Bm[(long)(n0 + m) * 128 + k0 + k4];
      Bl[k4 + 0][m] = b4.x; Bl[k4 + 1][m] = b4.y; Bl[k4 + 2][m] = b4.z; Bl[k4 + 3][m] = b4.w;
    }
    __syncthreads();
    #pragma unroll 8
    for (int k = 0; k < 64; ++k) {
      float a0 = Al[k][ty*4+0], a1 = Al[k][ty*4+1], a2 = Al[k][ty*4+2], a3 = Al[k][ty*4+3];
      float b0 = Bl[k][tx*4+0], b1 = Bl[k][tx*4+1], b2 = Bl[k][tx*4+2], b3 = Bl[k][tx*4+3];
      acc[0][0] += a0*b0; acc[0][1] += a0*b1; acc[0][2] += a0*b2; acc[0][3] += a0*b3;
      acc[1][0] += a1*b0; acc[1][1] += a1*b1; acc[1][2] += a1*b2; acc[1][3] += a1*b3;
      acc[2][0] += a2*b0; acc[2][1] += a2*b1; acc[2][2] += a2*b2; acc[2][3] += a2*b3;
      acc[3][0] += a3*b0; acc[3][1] += a3*b1; acc[3][2] += a3*b2; acc[3][3] += a3*b3;
    }
  }
  #pragma unroll
  for (int i = 0; i < 4; ++i) {
    #pragma unroll
    for (int j = 0; j < 4; ++j) {
      float bb = bias ? bias[n0 + tx*4 + j] : 0.f;
      C[(long)(m0 + ty*4 + i) * ldc + n0 + tx*4 + j] = acc[i][j] + bb;
    }
  }
}

// ---------------------------------------------------------------------------
__global__ __launch_bounds__(512) void cumsum_k(const float* __restrict__ Deltas,
                                                float* __restrict__ dcum)
{
  __shared__ float s[512];
  const int b = blockIdx.x, t = threadIdx.x;
  s[t] = Deltas[b * 512 + t];
  __syncthreads();
  for (int off = 1; off < 512; off <<= 1) {
    float v = (t >= off) ? s[t - off] : 0.f;
    __syncthreads();
    s[t] += v;
    __syncthreads();
  }
  dcum[b * 512 + t] = s[t];
}

// ---------------------------------------------------------------------------
__global__ __launch_bounds__(64) void softmax_k(float* __restrict__ a,
                                                const float* __restrict__ dcum)
{
  const int t = blockIdx.x, b = blockIdx.y;
  float* row = a + ((long)b * T_ + t) * T_;
  const int lane = threadIdx.x;
  if (t == 0) {
    #pragma unroll
    for (int i = 0; i < 8; ++i) row[i * 64 + lane] = 0.f;
    return;
  }
  float vals[8];
  float mx = -3.4e38f;
  #pragma unroll
  for (int i = 0; i < 8; ++i) {
    int j = i * 64 + lane;
    float v = (j < t) ? row[j] : -3.4e38f;
    vals[i] = v; mx = fmaxf(mx, v);
  }
  #pragma unroll
  for (int off = 1; off < 64; off <<= 1) mx = fmaxf(mx, __shfl_xor(mx, off));
  float sum = 0.f;
  #pragma unroll
  for (int i = 0; i < 8; ++i) {
    int j = i * 64 + lane;
    float e = (j < t) ? expf(vals[i] - mx) : 0.f;
    vals[i] = e; sum += e;
  }
  #pragma unroll
  for (int off = 1; off < 64; off <<= 1) sum += __shfl_xor(sum, off);
  const float E = 2.718281828459045f;
  const float dct = dcum[b * 512 + t];
  const float inv = 1.f / sum;
  #pragma unroll
  for (int i = 0; i < 8; ++i) {
    int j = i * 64 + lane;
    float w = (j < t) ? 1.f / logf(E + dct - dcum[b * 512 + j]) : 0.f;
    row[j] = vals[i] * inv * w;
  }
}

// ---------------------------------------------------------------------------
// Coherent (agent-scope, no-RMW) primitives.
// ---------------------------------------------------------------------------
__device__ __forceinline__ void st_wt(float* p, float v) {
  __hip_atomic_store(p, v, __ATOMIC_RELAXED, __HIP_MEMORY_SCOPE_AGENT);
}
__device__ __forceinline__ float ld_wt(const float* p) {
  return __hip_atomic_load(p, __ATOMIC_RELAXED, __HIP_MEMORY_SCOPE_AGENT);
}
__device__ __forceinline__ void flag_set(unsigned* f, unsigned v) {
  __hip_atomic_store(f, v, __ATOMIC_RELAXED, __HIP_MEMORY_SCOPE_AGENT);
}
// Wave-0 poll: lane i watches flags[i] (64 flags, one coalesced load/iter).
// No RMW anywhere -> no serialization. Returns abort indicator (uniform).
__device__ __forceinline__ int poll64(const unsigned* flags, unsigned target,
                                      unsigned* abrt) {
  long spins = 0;
  for (;;) {
    unsigned f = __hip_atomic_load(&flags[threadIdx.x], __ATOMIC_RELAXED,
                                   __HIP_MEMORY_SCOPE_AGENT);
    if (__all((int)(f >= target))) return 0;
    if (((++spins) & 63) == 0) {
      if (__hip_atomic_load(abrt, __ATOMIC_RELAXED, __HIP_MEMORY_SCOPE_AGENT)) return 1;
      if (spins > 1500000L) {
        __hip_atomic_store(abrt, 1u, __ATOMIC_RELAXED, __HIP_MEMORY_SCOPE_AGENT);
        return 1;
      }
    }
    __builtin_amdgcn_s_sleep(1);
  }
}

// ---------------------------------------------------------------------------
// Persistent recurrent kernel. 256 blocks x 256 threads, 1 block/CU.
// Sync via per-block monotone flags (stores) + 64-lane parallel polling;
// zero atomic RMW on the critical path. Release ordering: agent-scope data
// stores are drained by __syncthreads' vmcnt(0) before the flag store.
// The W_ih·v(t+1) partial is computed in the gates-wait window (v is known
// ahead of time), so only the W_hh·h dot sits on the recurrence chain.
// ---------------------------------------------------------------------------
__global__ __launch_bounds__(256, 1) void recurrent_k(
    const float* __restrict__ v_buf,   // [B][T][I]
    const float* __restrict__ alpha,   // [B][T][T]
    const float* __restrict__ W_ih,    // [4H][I]
    const float* __restrict__ W_hh,    // [4H][H]
    const float* __restrict__ b_ih, const float* __restrict__ b_hh,
    float* gates,                      // [B][4H] scratch (coherent traffic)
    float* out,                        // [B][T][H] = h_n (also h state)
    unsigned* bar)
{
  extern __shared__ float lds[];
  float* hv  = lds;                    // [8][512]  staged h(t-1)
  float* cn  = lds + 8 * 512;          // [512][64] cell history
  float* red = cn + 512 * 64;          // [256]
  __shared__ int s_ab;

  const int tid = threadIdx.x;
  const int g = blockIdx.x;
  const int grp = g >> 6;
  const int bg = grp;                       // G role: batches [8*bg, 8*bg+8)
  const int rs = g & 63;                    //         gate rows [rs*32, ...)
  const int b_u = g >> 3, hs = g & 7;       // U role
  const int r_l = tid >> 3, cg = tid & 7;   // G thread
  const int row = rs * 32 + r_l;
  const int jg = tid >> 6, l = tid & 63;    // U thread

  unsigned* flagA = bar;                    // [256] h(t) done markers
  unsigned* flagB = bar + 256;              // [256] gates(t) done markers
  unsigned* abrt  = bar + 512;
  const unsigned* fA = flagA + grp * 64;
  const unsigned* fB = flagB + grp * 64;

  // stationary weights: cols c = cg*4 + k*32
  float4 wh[16];
  #pragma unroll
  for (int k = 0; k < 16; ++k)
    wh[k] = *(const float4*)&W_hh[(long)row * H_ + cg * 4 + k * 32];
  float4 wv[4];
  #pragma unroll
  for (int k = 0; k < 4; ++k)
    wv[k] = *(const float4*)&W_ih[(long)row * I_ + cg * 4 + k * 32];
  const float bias = b_ih[row] + b_hh[row];

  // vacc(0): W_ih · v(b, 0) partial over this cg's 32 columns
  float vacc[8];
  #pragma unroll
  for (int bp = 0; bp < 8; ++bp) {
    float a = 0.f;
    #pragma unroll
    for (int k = 0; k < 4; ++k) {
      float4 x = *(const float4*)&v_buf[((long)(bg * 8 + bp) * T_) * I_ + cg * 4 + k * 32];
      a += wv[k].x * x.x + wv[k].y * x.y + wv[k].z * x.z + wv[k].w * x.w;
    }
    vacc[bp] = a;
  }

  for (int t = 0; t < T_; ++t) {
    // ---- wait: h(t-1) ready (all group flagA >= t; trivial at t=0) ----
    if (tid < 64) { int ab = poll64(fA, (unsigned)t, abrt); if (tid == 0) s_ab = ab; }
    __syncthreads();
    if (s_ab) return;

    if (t > 0) {
      // stage h(t-1) for the 8 G-batches (coherent loads -> LDS)
      #pragma unroll
      for (int s = 0; s < 16; ++s) {
        int idx = tid + s * 256;
        int bp = idx >> 9, c = idx & 511;
        hv[bp * 512 + c] = ld_wt(&out[((long)(bg * 8 + bp) * T_ + (t - 1)) * H_ + c]);
      }
      __syncthreads();
    }

    // ---- G: acc = vacc + W_hh·h partial over this cg's 64 h-columns ----
    float acc[8];
    #pragma unroll
    for (int bp = 0; bp < 8; ++bp) acc[bp] = vacc[bp];
    if (t > 0) {
      #pragma unroll
      for (int k = 0; k < 16; ++k) {
        float4 w4 = wh[k];
        #pragma unroll
        for (int bp = 0; bp < 8; ++bp) {
          float4 x = *(const float4*)&hv[bp * 512 + cg * 4 + k * 32];
          acc[bp] += w4.x * x.x + w4.y * x.y + w4.z * x.z + w4.w * x.w;
        }
      }
    }
    #pragma unroll
    for (int off = 1; off < 8; off <<= 1) {
      #pragma unroll
      for (int bp = 0; bp < 8; ++bp) acc[bp] += __shfl_xor(acc[bp], off);
    }
    if (cg == 0) {
      #pragma unroll
      for (int bp = 0; bp < 8; ++bp)
        st_wt(&gates[(long)(bg * 8 + bp) * G4_ + row], acc[bp] + bias);
    }
    __syncthreads();                          // drains all gate stores
    if (tid == 0) flag_set(&flagB[g], (unsigned)(t + 1));

    // ---- window work (off critical path) ----
    // vacc(t+1): v is input-known, no dependency
    if (t + 1 < T_) {
      #pragma unroll
      for (int bp = 0; bp < 8; ++bp) {
        float a = 0.f;
        #pragma unroll
        for (int k = 0; k < 4; ++k) {
          float4 x = *(const float4*)&v_buf[((long)(bg * 8 + bp) * T_ + (t + 1)) * I_ + cg * 4 + k * 32];
          a += wv[k].x * x.x + wv[k].y * x.y + wv[k].z * x.z + wv[k].w * x.w;
        }
        vacc[bp] = a;
      }
    }
    // C partial: depends only on alpha + cn (history), not on gates
    float partial = 0.f;
    {
      const float* arow = alpha + ((long)b_u * T_ + t) * T_;
      int j0 = jg * 128, j1 = j0 + 128; if (j1 > t) j1 = t;
      for (int j = j0; j < j1; ++j)
        partial += arow[j] * cn[j * 64 + l];
    }
    red[tid] = partial;

    // ---- wait: gates(t) ready (all group flagB >= t+1) ----
    if (tid < 64) { int ab = poll64(fB, (unsigned)(t + 1), abrt); if (tid == 0) s_ab = ab; }
    __syncthreads();                          // red[] visible + s_ab broadcast
    if (s_ab) return;

    // ---- U finish: gates -> (i,f,g,o), cell/hidden update ----
    if (tid < 64) {
      const long gb = (long)b_u * G4_ + hs * 64 + l;
      float gi = ld_wt(&gates[gb]);
      float gf = ld_wt(&gates[gb + H_]);
      float gg = ld_wt(&gates[gb + 2 * H_]);
      float go = ld_wt(&gates[gb + 3 * H_]);
      float C  = red[l] + red[64 + l] + red[128 + l] + red[192 + l];
      float si = 1.f / (1.f + expf(-gi));
      float sf = 1.f / (1.f + expf(-gf));
      float so = 1.f / (1.f + expf(-go));
      float cnew = sf * C + si * tanhf(gg);
      float hnew = so * tanhf(cnew);
      st_wt(&out[((long)b_u * T_ + t) * H_ + hs * 64 + l], hnew);
      cn[t * 64 + l] = cnew;
    }
    __syncthreads();                          // drains h stores
    if (tid == 0) flag_set(&flagA[g], (unsigned)(t + 1));
  }
}

// ---------------------------------------------------------------------------
extern "C" void kernel_launch(void* const* d_in, const int* in_sizes, int n_in,
                              void* d_out, int out_size, void* d_ws, size_t ws_size,
                              hipStream_t stream)
{
  const float* values  = (const float*)d_in[0];
  const float* Deltas  = (const float*)d_in[1];
  // d_in[2] = ys (unused by the reference computation)
  const float* W_ih    = (const float*)d_in[3];
  const float* W_hh    = (const float*)d_in[4];
  const float* b_ih    = (const float*)d_in[5];
  const float* b_hh    = (const float*)d_in[6];
  const float* atten_W = (const float*)d_in[7];
  const float* atten_b = (const float*)d_in[8];
  float* out = (float*)d_out;

  char* ws = (char*)d_ws;
  unsigned* bar = (unsigned*)ws;                       // 4 KB (flags)
  float* v_buf  = (float*)(ws + 4096);                 // 8 MB   [B][T][I]
  float* a_buf  = (float*)(ws + 4096 + 8388608);       // 32 MB  [B][T][T]
  float* dcum   = (float*)(ws + 4096 + 8388608 + 33554432);            // 64 KB
  float* gates  = (float*)(ws + 4096 + 8388608 + 33554432 + 65536);    // 256 KB

  hipMemsetAsync(bar, 0, 4096, stream);

  // v = values @ atten_W^T + atten_b   (M=B*T=16384, N=128, K=128)
  gemm_abt<<<dim3(256, 2, 1), 256, 0, stream>>>(values, atten_W, v_buf, atten_b,
                                                0, 0, 0, 128);
  cumsum_k<<<32, 512, 0, stream>>>(Deltas, dcum);
  // a[b,t,j] = v[b,t,:] . values[b,j,:]   (per-batch 512x512x128)
  gemm_abt<<<dim3(8, 8, 32), 256, 0, stream>>>(v_buf, values, a_buf, nullptr,
                                               512L * 128, 512L * 128, 512L * 512, 512);
  softmax_k<<<dim3(512, 32), 64, 0, stream>>>(a_buf, dcum);

  (void)hipFuncSetAttribute((const void*)recurrent_k,
                            hipFuncAttributeMaxDynamicSharedMemorySize, 148480);
  recurrent_k<<<256, 256, 148480, stream>>>(v_buf, a_buf, W_ih, W_hh, b_ih, b_hh,
                                            gates, out, bar);
}

// Round 7
// 17124.980 us; speedup vs baseline: 1.0032x; 1.0032x over previous
//
#include <hip/hip_runtime.h>
#include <math.h>

#define B_  32
#define T_  512
#define I_  128
#define H_  512
#define G4_ 2048   // 4*H
#define GB_ 64     // blocks per sync group (dependency-closed)

// ---------------------------------------------------------------------------
// Tiled fp32 GEMM: C[m][n] = sum_k A[m][k] * Bm[n][k]  (+ bias[n] if bias)
// ---------------------------------------------------------------------------
__global__ __launch_bounds__(256) void gemm_abt(
    const float* __restrict__ A, const float* __restrict__ Bm, float* __restrict__ C,
    const float* __restrict__ bias, long sA, long sB, long sC, int ldc)
{
  __shared__ float Al[64][65];
  __shared__ float Bl[64][65];
  const long z = blockIdx.z;
  A += z * sA; Bm += z * sB; C += z * sC;
  const int m0 = blockIdx.x * 64, n0 = blockIdx.y * 64;
  const int tid = threadIdx.x;
  const int tx = tid & 15, ty = tid >> 4;
  float acc[4][4] = {};

  for (int h = 0; h < 2; ++h) {
    const int k0 = h * 64;
    __syncthreads();
    #pragma unroll
    for (int s = 0; s < 4; ++s) {
      int idx = tid + s * 256;
      int m  = idx >> 4;
      int k4 = (idx & 15) << 2;
      float4 a4 = *(const float4*)&A[(long)(m0 + m) * 128 + k0 + k4];
      Al[k4 + 0][m] = a4.x; Al[k4 + 1][m] = a4.y; Al[k4 + 2][m] = a4.z; Al[k4 + 3][m] = a4.w;
      float4 b4 = *(const float4*)&Bm[(long)(n0 + m) * 128 + k0 + k4];
      Bl[k4 + 0][m] = b4.x; Bl[k4 + 1][m] = b4.y; Bl[k4 + 2][m] = b4.z; Bl[k4 + 3][m] = b4.w;
    }
    __syncthreads();
    #pragma unroll 8
    for (int k = 0; k < 64; ++k) {
      float a0 = Al[k][ty*4+0], a1 = Al[k][ty*4+1], a2 = Al[k][ty*4+2], a3 = Al[k][ty*4+3];
      float b0 = Bl[k][tx*4+0], b1 = Bl[k][tx*4+1], b2 = Bl[k][tx*4+2], b3 = Bl[k][tx*4+3];
      acc[0][0] += a0*b0; acc[0][1] += a0*b1; acc[0][2] += a0*b2; acc[0][3] += a0*b3;
      acc[1][0] += a1*b0; acc[1][1] += a1*b1; acc[1][2] += a1*b2; acc[1][3] += a1*b3;
      acc[2][0] += a2*b0; acc[2][1] += a2*b1; acc[2][2] += a2*b2; acc[2][3] += a2*b3;
      acc[3][0] += a3*b0; acc[3][1] += a3*b1; acc[3][2] += a3*b2; acc[3][3] += a3*b3;
    }
  }
  #pragma unroll
  for (int i = 0; i < 4; ++i) {
    #pragma unroll
    for (int j = 0; j < 4; ++j) {
      float bb = bias ? bias[n0 + tx*4 + j] : 0.f;
      C[(long)(m0 + ty*4 + i) * ldc + n0 + tx*4 + j] = acc[i][j] + bb;
    }
  }
}

// ---------------------------------------------------------------------------
__global__ __launch_bounds__(512) void cumsum_k(const float* __restrict__ Deltas,
                                                float* __restrict__ dcum)
{
  __shared__ float s[512];
  const int b = blockIdx.x, t = threadIdx.x;
  s[t] = Deltas[b * 512 + t];
  __syncthreads();
  for (int off = 1; off < 512; off <<= 1) {
    float v = (t >= off) ? s[t - off] : 0.f;
    __syncthreads();
    s[t] += v;
    __syncthreads();
  }
  dcum[b * 512 + t] = s[t];
}

// ---------------------------------------------------------------------------
__global__ __launch_bounds__(64) void softmax_k(float* __restrict__ a,
                                                const float* __restrict__ dcum)
{
  const int t = blockIdx.x, b = blockIdx.y;
  float* row = a + ((long)b * T_ + t) * T_;
  const int lane = threadIdx.x;
  if (t == 0) {
    #pragma unroll
    for (int i = 0; i < 8; ++i) row[i * 64 + lane] = 0.f;
    return;
  }
  float vals[8];
  float mx = -3.4e38f;
  #pragma unroll
  for (int i = 0; i < 8; ++i) {
    int j = i * 64 + lane;
    float v = (j < t) ? row[j] : -3.4e38f;
    vals[i] = v; mx = fmaxf(mx, v);
  }
  #pragma unroll
  for (int off = 1; off < 64; off <<= 1) mx = fmaxf(mx, __shfl_xor(mx, off));
  float sum = 0.f;
  #pragma unroll
  for (int i = 0; i < 8; ++i) {
    int j = i * 64 + lane;
    float e = (j < t) ? expf(vals[i] - mx) : 0.f;
    vals[i] = e; sum += e;
  }
  #pragma unroll
  for (int off = 1; off < 64; off <<= 1) sum += __shfl_xor(sum, off);
  const float E = 2.718281828459045f;
  const float dct = dcum[b * 512 + t];
  const float inv = 1.f / sum;
  #pragma unroll
  for (int i = 0; i < 8; ++i) {
    int j = i * 64 + lane;
    float w = (j < t) ? 1.f / logf(E + dct - dcum[b * 512 + j]) : 0.f;
    row[j] = vals[i] * inv * w;
  }
}

// ---------------------------------------------------------------------------
// Agent-scope (coherence-point) primitives. All flags sit on PRIVATE 64 B
// lines: one writer, at most one polling requester per line -> no same-line
// service serialization at the coherence point (the R4/R6 16 us/hop wall).
// ---------------------------------------------------------------------------
__device__ __forceinline__ void st_wt(float* p, float v) {
  __hip_atomic_store(p, v, __ATOMIC_RELAXED, __HIP_MEMORY_SCOPE_AGENT);
}
__device__ __forceinline__ float ld_wt(const float* p) {
  return __hip_atomic_load(p, __ATOMIC_RELAXED, __HIP_MEMORY_SCOPE_AGENT);
}
__device__ __forceinline__ void stflag(unsigned* p, unsigned v) {
  __hip_atomic_store(p, v, __ATOMIC_RELAXED, __HIP_MEMORY_SCOPE_AGENT);
}
__device__ __forceinline__ unsigned ldflag(const unsigned* p) {
  return __hip_atomic_load(p, __ATOMIC_RELAXED, __HIP_MEMORY_SCOPE_AGENT);
}
// Poll per-lane address until value >= target (wave-uniform exit).
__device__ __forceinline__ int pollv(const unsigned* p, unsigned target,
                                     unsigned* abrt) {
  long spins = 0;
  for (;;) {
    unsigned f = ldflag(p);
    if (__all((int)(f >= target))) return 0;
    if (((++spins) & 63) == 0) {
      if (ldflag(abrt)) return 1;
      if (spins > 400000L) {
        __hip_atomic_store(abrt, 1u, __ATOMIC_RELAXED, __HIP_MEMORY_SCOPE_AGENT);
        return 1;
      }
    }
    __builtin_amdgcn_s_sleep(1);
  }
}

// ---------------------------------------------------------------------------
// Persistent recurrent kernel. 256 blocks x 256 threads, 1 block/CU.
// Per 64-block group, per phase: producers store private flag lines
// (fire-and-forget); ONE leader block polls the 64 producer lines (single
// requester per line) and rebroadcasts with one wave-wide store to 64
// private mailbox lines; each consumer polls only its own mailbox line.
// Leaders differ per phase (LA=grp*64, LB=grp*64+1) so aggregation lag
// doesn't compound within a step.
// ---------------------------------------------------------------------------
__global__ __launch_bounds__(256, 1) void recurrent_k(
    const float* __restrict__ v_buf,   // [B][T][I]
    const float* __restrict__ alpha,   // [B][T][T]
    const float* __restrict__ W_ih,    // [4H][I]
    const float* __restrict__ W_hh,    // [4H][H]
    const float* __restrict__ b_ih, const float* __restrict__ b_hh,
    float* gates,                      // [B][4H] scratch (coherent traffic)
    float* out,                        // [B][T][H] = h_n (also h state)
    unsigned* bar)
{
  extern __shared__ float lds[];
  float* hv  = lds;                    // [8][512]  staged h(t-1)
  float* cn  = lds + 8 * 512;          // [512][64] cell history
  float* red = cn + 512 * 64;          // [256]
  __shared__ int s_ab;

  const int tid = threadIdx.x;
  const int g = blockIdx.x;
  const int grp = g >> 6;
  const int bg = grp;                       // G role: batches [8*bg, 8*bg+8)
  const int rs = g & 63;                    //         gate rows [rs*32, ...)
  const int b_u = g >> 3, hs = g & 7;       // U role
  const int r_l = tid >> 3, cg = tid & 7;   // G thread
  const int row = rs * 32 + r_l;
  const int jg = tid >> 6, l = tid & 63;    // U thread

  // flag regions: dword index = block*16 (64 B line stride)
  unsigned* pflagA = bar;                   // producers: h(t) done
  unsigned* pflagB = bar + 4096;            // producers: gates(t) done
  unsigned* mailA  = bar + 8192;            // leader->consumer broadcasts
  unsigned* mailB  = bar + 12288;
  unsigned* abrt   = bar + 16384;
  const int LA = grp * 64, LB = grp * 64 + 1;
  const int gl = grp * 64 + (tid & 63);     // leader-poll target block

  // stationary weights: cols c = cg*4 + k*32
  float4 wh[16];
  #pragma unroll
  for (int k = 0; k < 16; ++k)
    wh[k] = *(const float4*)&W_hh[(long)row * H_ + cg * 4 + k * 32];
  float4 wv[4];
  #pragma unroll
  for (int k = 0; k < 4; ++k)
    wv[k] = *(const float4*)&W_ih[(long)row * I_ + cg * 4 + k * 32];
  const float bias = b_ih[row] + b_hh[row];

  // vacc(0): W_ih . v(b, 0) partial over this cg's 32 columns
  float vacc[8];
  #pragma unroll
  for (int bp = 0; bp < 8; ++bp) {
    float a = 0.f;
    #pragma unroll
    for (int k = 0; k < 4; ++k) {
      float4 x = *(const float4*)&v_buf[((long)(bg * 8 + bp) * T_) * I_ + cg * 4 + k * 32];
      a += wv[k].x * x.x + wv[k].y * x.y + wv[k].z * x.z + wv[k].w * x.w;
    }
    vacc[bp] = a;
  }

  for (int t = 0; t < T_; ++t) {
    // ---- phase A wait: h(t-1) visible (own mailbox only; trivial t=0) ----
    if (tid < 64) {
      int ab = pollv(&mailA[(long)g * 16], (unsigned)t, abrt);
      if (tid == 0) s_ab = ab;
    }
    __syncthreads();
    if (s_ab) return;

    if (t > 0) {
      // stage h(t-1) for the 8 G-batches (coherent loads -> LDS)
      #pragma unroll
      for (int s = 0; s < 16; ++s) {
        int idx = tid + s * 256;
        int bp = idx >> 9, c = idx & 511;
        hv[bp * 512 + c] = ld_wt(&out[((long)(bg * 8 + bp) * T_ + (t - 1)) * H_ + c]);
      }
      __syncthreads();
    }

    // ---- G: acc = vacc + W_hh.h partial over this cg's 64 h-columns ----
    float acc[8];
    #pragma unroll
    for (int bp = 0; bp < 8; ++bp) acc[bp] = vacc[bp];
    if (t > 0) {
      #pragma unroll
      for (int k = 0; k < 16; ++k) {
        float4 w4 = wh[k];
        #pragma unroll
        for (int bp = 0; bp < 8; ++bp) {
          float4 x = *(const float4*)&hv[bp * 512 + cg * 4 + k * 32];
          acc[bp] += w4.x * x.x + w4.y * x.y + w4.z * x.z + w4.w * x.w;
        }
      }
    }
    #pragma unroll
    for (int off = 1; off < 8; off <<= 1) {
      #pragma unroll
      for (int bp = 0; bp < 8; ++bp) acc[bp] += __shfl_xor(acc[bp], off);
    }
    if (cg == 0) {
      #pragma unroll
      for (int bp = 0; bp < 8; ++bp)
        st_wt(&gates[(long)(bg * 8 + bp) * G4_ + row], acc[bp] + bias);
    }
    __syncthreads();                          // drains all gate stores
    if (tid == 0) stflag(&pflagB[(long)g * 16], (unsigned)(t + 1));

    // leader B: aggregate producer flags, rebroadcast to private mailboxes
    if (g == LB && tid < 64) {
      int ab = pollv(&pflagB[(long)gl * 16], (unsigned)(t + 1), abrt);
      if (!ab) stflag(&mailB[(long)gl * 16], (unsigned)(t + 1));
    }

    // ---- window work (off critical path) ----
    if (t + 1 < T_) {                          // vacc(t+1): input-known
      #pragma unroll
      for (int bp = 0; bp < 8; ++bp) {
        float a = 0.f;
        #pragma unroll
        for (int k = 0; k < 4; ++k) {
          float4 x = *(const float4*)&v_buf[((long)(bg * 8 + bp) * T_ + (t + 1)) * I_ + cg * 4 + k * 32];
          a += wv[k].x * x.x + wv[k].y * x.y + wv[k].z * x.z + wv[k].w * x.w;
        }
        vacc[bp] = a;
      }
    }
    float partial = 0.f;                       // C partial: alpha . cn history
    {
      const float* arow = alpha + ((long)b_u * T_ + t) * T_;
      int j0 = jg * 128, j1 = j0 + 128; if (j1 > t) j1 = t;
      for (int j = j0; j < j1; ++j)
        partial += arow[j] * cn[j * 64 + l];
    }
    red[tid] = partial;

    // ---- phase B wait: gates(t) visible (own mailbox only) ----
    if (tid < 64) {
      int ab = pollv(&mailB[(long)g * 16], (unsigned)(t + 1), abrt);
      if (tid == 0) s_ab = ab;
    }
    __syncthreads();                           // red[] visible + s_ab bcast
    if (s_ab) return;

    // ---- U finish: gates -> (i,f,g,o), cell/hidden update ----
    if (tid < 64) {
      const long gb = (long)b_u * G4_ + hs * 64 + l;
      float gi = ld_wt(&gates[gb]);
      float gf = ld_wt(&gates[gb + H_]);
      float gg = ld_wt(&gates[gb + 2 * H_]);
      float go = ld_wt(&gates[gb + 3 * H_]);
      float C  = red[l] + red[64 + l] + red[128 + l] + red[192 + l];
      float si = 1.f / (1.f + expf(-gi));
      float sf = 1.f / (1.f + expf(-gf));
      float so = 1.f / (1.f + expf(-go));
      float cnew = sf * C + si * tanhf(gg);
      float hnew = so * tanhf(cnew);
      st_wt(&out[((long)b_u * T_ + t) * H_ + hs * 64 + l], hnew);
      cn[t * 64 + l] = cnew;
    }
    __syncthreads();                           // drains h stores
    if (tid == 0) stflag(&pflagA[(long)g * 16], (unsigned)(t + 1));

    // leader A: aggregate h flags, rebroadcast
    if (g == LA && tid < 64) {
      int ab = pollv(&pflagA[(long)gl * 16], (unsigned)(t + 1), abrt);
      if (!ab) stflag(&mailA[(long)gl * 16], (unsigned)(t + 1));
    }
  }
}

// ---------------------------------------------------------------------------
extern "C" void kernel_launch(void* const* d_in, const int* in_sizes, int n_in,
                              void* d_out, int out_size, void* d_ws, size_t ws_size,
                              hipStream_t stream)
{
  const float* values  = (const float*)d_in[0];
  const float* Deltas  = (const float*)d_in[1];
  // d_in[2] = ys (unused by the reference computation)
  const float* W_ih    = (const float*)d_in[3];
  const float* W_hh    = (const float*)d_in[4];
  const float* b_ih    = (const float*)d_in[5];
  const float* b_hh    = (const float*)d_in[6];
  const float* atten_W = (const float*)d_in[7];
  const float* atten_b = (const float*)d_in[8];
  float* out = (float*)d_out;

  char* ws = (char*)d_ws;
  unsigned* bar = (unsigned*)ws;                       // 68 KB flag region
  float* v_buf  = (float*)(ws + 69632);                // 8 MB   [B][T][I]
  float* a_buf  = (float*)(ws + 69632 + 8388608);      // 32 MB  [B][T][T]
  float* dcum   = (float*)(ws + 69632 + 8388608 + 33554432);            // 64 KB
  float* gates  = (float*)(ws + 69632 + 8388608 + 33554432 + 65536);    // 256 KB

  hipMemsetAsync(bar, 0, 69632, stream);

  // v = values @ atten_W^T + atten_b   (M=B*T=16384, N=128, K=128)
  gemm_abt<<<dim3(256, 2, 1), 256, 0, stream>>>(values, atten_W, v_buf, atten_b,
                                                0, 0, 0, 128);
  cumsum_k<<<32, 512, 0, stream>>>(Deltas, dcum);
  // a[b,t,j] = v[b,t,:] . values[b,j,:]   (per-batch 512x512x128)
  gemm_abt<<<dim3(8, 8, 32), 256, 0, stream>>>(v_buf, values, a_buf, nullptr,
                                               512L * 128, 512L * 128, 512L * 512, 512);
  softmax_k<<<dim3(512, 32), 64, 0, stream>>>(a_buf, dcum);

  (void)hipFuncSetAttribute((const void*)recurrent_k,
                            hipFuncAttributeMaxDynamicSharedMemorySize, 148480);
  recurrent_k<<<256, 256, 148480, stream>>>(v_buf, a_buf, W_ih, W_hh, b_ih, b_hh,
                                            gates, out, bar);
}